// Round 6
// baseline (544.509 us; speedup 1.0000x reference)
//
#include <hip/hip_runtime.h>
#include <hip/hip_bf16.h>

#define B_ 4
#define S_ 2048
#define HID_ 2048
#define NH_ 8
#define HD_ 256
#define QKVN 2560

typedef unsigned short u16;
typedef unsigned long long ull;
typedef __attribute__((ext_vector_type(4))) float f32x4;
typedef __attribute__((ext_vector_type(16))) float f32x16;
typedef __attribute__((ext_vector_type(8))) short bf16x8;

__device__ __forceinline__ float bf2f(u16 u) {
  union { unsigned int i; float f; } v; v.i = ((unsigned int)u) << 16; return v.f;
}
__device__ __forceinline__ u16 f2bf(float f) {
  union { unsigned int i; float f; } v; v.f = f;
  unsigned int r = v.i + 0x7fffu + ((v.i >> 16) & 1u);
  return (u16)(r >> 16);
}

// ---------------- cast x (f32 -> bf16), 8 elems/thread ----------------
__global__ void cast_f32_bf16(const float* __restrict__ in, u16* __restrict__ out, int n8) {
  int i = blockIdx.x * blockDim.x + threadIdx.x;
  int stride = gridDim.x * blockDim.x;
  for (; i < n8; i += stride) {
    const float4* p = (const float4*)(in + (size_t)i * 8);
    float4 a = p[0], b = p[1];
    u16 o[8] = {f2bf(a.x), f2bf(a.y), f2bf(a.z), f2bf(a.w),
                f2bf(b.x), f2bf(b.y), f2bf(b.z), f2bf(b.w)};
    *(uint4*)(out + (size_t)i * 8) = *(const uint4*)o;
  }
}

// ------------- transpose + cast: in[R][C] f32 -> out[C][R] bf16 -------------
__global__ void transpose_cast(const float* __restrict__ in, u16* __restrict__ out, int R, int C) {
  __shared__ float t[32][33];
  int c0 = blockIdx.x * 32, r0 = blockIdx.y * 32;
  int tx = threadIdx.x, ty = threadIdx.y;
#pragma unroll
  for (int i = 0; i < 4; ++i)
    t[ty + i * 8][tx] = in[(size_t)(r0 + ty + i * 8) * C + c0 + tx];
  __syncthreads();
#pragma unroll
  for (int i = 0; i < 4; ++i)
    out[(size_t)(c0 + ty + i * 8) * R + r0 + tx] = f2bf(t[tx][ty + i * 8]);
}

// ------------- transpose bf16 (per-batch): in[R][C] -> out[C][R] -------------
__global__ void transpose_bf16(const u16* __restrict__ in, u16* __restrict__ out, int R, int C) {
  __shared__ u16 t[32][33];
  in += (size_t)blockIdx.z * R * C;
  out += (size_t)blockIdx.z * R * C;
  int c0 = blockIdx.x * 32, r0 = blockIdx.y * 32;
  int tx = threadIdx.x, ty = threadIdx.y;
#pragma unroll
  for (int i = 0; i < 4; ++i)
    t[ty + i * 8][tx] = in[(size_t)(r0 + ty + i * 8) * C + c0 + tx];
  __syncthreads();
#pragma unroll
  for (int i = 0; i < 4; ++i)
    out[(size_t)(c0 + ty + i * 8) * R + r0 + tx] = t[tx][ty + i * 8];
}

// ---------------- m97-style bf16 GEMM: C[M][N] = A[M][K] * BT[N][K]^T + bias ----------------
template <bool OUT_F32>
__global__ __launch_bounds__(256) void gemm_bt(const u16* __restrict__ A, const u16* __restrict__ BT,
                                               const float* __restrict__ bias, void* __restrict__ Cout,
                                               int M, int N, int K) {
  __shared__ u16 As[128 * 32];
  __shared__ u16 Bs[128 * 32];
  int nwg = gridDim.x;
  int bid = (int)blockIdx.x;
  bid = (bid & 7) * (nwg >> 3) + (bid >> 3);  // XCD swizzle (nwg % 8 == 0)
  int ntiles = N >> 7;
  int m0 = (bid / ntiles) << 7, n0 = (bid % ntiles) << 7;
  int tid = threadIdx.x, w = tid >> 6, lane = tid & 63;
  int wr = w >> 1, wc = w & 1;
  int l15 = lane & 15, lg = lane >> 4;
  f32x4 acc[4][4] = {};
  int crow = lane >> 2;
  int ccol = (lane & 3) * 8;
  for (int k0 = 0; k0 < K; k0 += 32) {
#pragma unroll
    for (int i = 0; i < 2; ++i) {
      int c = w * 2 + i;
      const u16* ga = A + (size_t)(m0 + c * 16 + crow) * K + k0 + ccol;
      const u16* gb = BT + (size_t)(n0 + c * 16 + crow) * K + k0 + ccol;
      __builtin_amdgcn_global_load_lds((const __attribute__((address_space(1))) void*)ga,
                                       (__attribute__((address_space(3))) void*)(As + c * 512), 16, 0, 0);
      __builtin_amdgcn_global_load_lds((const __attribute__((address_space(1))) void*)gb,
                                       (__attribute__((address_space(3))) void*)(Bs + c * 512), 16, 0, 0);
    }
    __syncthreads();
    bf16x8 af[4], bfr[4];
#pragma unroll
    for (int r = 0; r < 4; ++r)
      af[r] = *(const bf16x8*)&As[(wr * 64 + r * 16 + l15) * 32 + lg * 8];
#pragma unroll
    for (int c = 0; c < 4; ++c)
      bfr[c] = *(const bf16x8*)&Bs[(wc * 64 + c * 16 + l15) * 32 + lg * 8];
#pragma unroll
    for (int r = 0; r < 4; ++r)
#pragma unroll
      for (int c = 0; c < 4; ++c)
        acc[r][c] = __builtin_amdgcn_mfma_f32_16x16x32_bf16(af[r], bfr[c], acc[r][c], 0, 0, 0);
    __syncthreads();
  }
#pragma unroll
  for (int r = 0; r < 4; ++r) {
    int mrow = m0 + wr * 64 + r * 16 + lg * 4;
#pragma unroll
    for (int c = 0; c < 4; ++c) {
      int col = n0 + wc * 64 + c * 16 + l15;
      float bv = bias[col];
#pragma unroll
      for (int j = 0; j < 4; ++j) {
        float v = acc[r][c][j] + bv;
        if (OUT_F32)
          ((float*)Cout)[(size_t)(mrow + j) * N + col] = v;
        else
          ((u16*)Cout)[(size_t)(mrow + j) * N + col] = f2bf(v);
      }
    }
  }
}

// ---------------- RoPE + scatter qkv -> q_pack [b][s][h][d] / k / v (bf16) ----------------
// q scaled by HD^-0.5 * log2(e) (scores consumed in exp2 domain).
__global__ void rope_scatter(const u16* __restrict__ qkv, const float* __restrict__ freqs,
                             u16* __restrict__ qo, u16* __restrict__ ko, u16* __restrict__ vo) {
  const int per_row = QKVN / 8;  // 320
  const int total = B_ * S_ * per_row;
  int i = blockIdx.x * blockDim.x + threadIdx.x;
  int stride = gridDim.x * blockDim.x;
  for (; i < total; i += stride) {
    int m = i / per_row;
    int n8 = (i - m * per_row) * 8;
    int b = m >> 11, s = m & 2047;
    uint4 raw = *(const uint4*)(qkv + (size_t)m * QKVN + n8);
    const u16* u = (const u16*)&raw;
    if (n8 < 2304) {
      int d = (n8 < 2048) ? (n8 & 255) : (n8 - 2048);
      float scl = (n8 < 2048) ? (0.0625f * 1.44269504f) : 1.0f;
      const float* fp = freqs + ((size_t)s * 128 + (d >> 1)) * 2;
      float4 f0 = *(const float4*)fp;
      float4 f1 = *(const float4*)(fp + 4);
      float fc[8] = {f0.x, f0.y, f0.z, f0.w, f1.x, f1.y, f1.z, f1.w};
      u16 o[8];
#pragma unroll
      for (int p = 0; p < 4; ++p) {
        float r = bf2f(u[2 * p]), im = bf2f(u[2 * p + 1]);
        float c = fc[2 * p], sn = fc[2 * p + 1];
        o[2 * p] = f2bf((r * c - im * sn) * scl);
        o[2 * p + 1] = f2bf((r * sn + im * c) * scl);
      }
      u16* dst;
      if (n8 < 2048) {
        dst = qo + (size_t)m * 2048 + n8;  // packed [b][s][h][d]
      } else {
        dst = ko + (((size_t)m) << 8) + d;
      }
      *(uint4*)dst = *(const uint4*)o;
    } else {
      int d = n8 - 2304;
      *(uint4*)(vo + (((size_t)m) << 8) + d) = raw;
    }
  }
}

// ---------------- flash attention, GQA head-packed, bf16 32x32x16 MFMA ----------------
// QBLK=128 q-rows (16 s x 8 heads), 4 waves x 32 q. KBLK=32. Grid 512 -> 2 blocks/CU.
// K double-buffered via global_load_lds (pre-swizzled source); V single 32KB buffer,
// 128B rows hold two kt-halves (alternating dbuf), staged global->reg->swizzled ds_write.
// Swapped QK^T (mfma(K,Q)) -> lane owns q=lane&31; in-register P via permlane32_swap.
// Work balance: bid and bid+256 process complementary s-tiles (t, 127-t).

#define STAGE_K(dst, kt)                                                                          \
  do {                                                                                            \
    _Pragma("unroll") for (int _p = 0; _p < 4; ++_p) {                                            \
      int _idx = _p * 256 + tid;                                                                  \
      int _row = _idx >> 5, _c = _idx & 31;                                                       \
      const u16* _src = Kg + ((size_t)(b * S_ + (kt) * 32 + _row)) * HD_ +                        \
                        ((((_c * 16) ^ ((_row & 7) << 4))) >> 1);                                 \
      __builtin_amdgcn_global_load_lds((const __attribute__((address_space(1))) void*)_src,       \
                                       (__attribute__((address_space(3))) void*)((dst) + _idx * 8), 16, 0, 0); \
    }                                                                                             \
  } while (0)

#define LOAD_V(vst, kt)                                                                           \
  do {                                                                                            \
    _Pragma("unroll") for (int _p = 0; _p < 4; ++_p) {                                            \
      int _idx = _p * 256 + tid;                                                                  \
      int _d = _idx >> 2, _c = _idx & 3;                                                          \
      vst[_p] = *(const uint4*)(VTp + ((size_t)(b * 256 + _d)) * S_ + (kt) * 32 + _c * 8);        \
    }                                                                                             \
  } while (0)

#define WRITE_V(vst, kt)                                                                          \
  do {                                                                                            \
    int _hh = (kt) & 1;                                                                           \
    _Pragma("unroll") for (int _p = 0; _p < 4; ++_p) {                                            \
      int _idx = _p * 256 + tid;                                                                  \
      int _d = _idx >> 2, _c = _idx & 3;                                                          \
      *(uint4*)((char*)Vs + _d * 128 + ((_hh * 64 + _c * 16) ^ ((_d & 7) << 4))) = vst[_p];       \
    }                                                                                             \
  } while (0)

__global__ __launch_bounds__(256, 2) void flash_attn(const u16* __restrict__ Qp, const u16* __restrict__ Kg,
                                                     const u16* __restrict__ VTp, u16* __restrict__ Op) {
  __shared__ u16 Ks[2][32 * 256];  // 2 x 16 KB, rows 512B, XOR-swizzled
  __shared__ u16 Vs[256 * 64];     // 32 KB: [256 d][128B = 2 halves x 32 k], XOR-swizzled
  int bid = (int)blockIdx.x;
  int easy = bid >> 8;        // 0: t in [64,127] desc; 1: t in [0,63] asc (complement pairing)
  int j = bid & 255;
  int b = j >> 6, r = j & 63;
  int t = easy ? r : (127 - r);
  int tid = threadIdx.x;
  int w = tid >> 6, l = tid & 63;
  int l31 = l & 31, lh = l >> 5;
  int q_local = w * 32 + l31;
  size_t qrow = (size_t)b * 16384 + (size_t)t * 128 + q_local;
  int s_g = t * 16 + (q_local >> 3);  // this lane's s position

  // Q B-fragments: 16 hd-steps; lane holds Q[q=l31][hd = st*16 + lh*8 + e]
  bf16x8 qf[16];
  const u16* qp = Qp + qrow * HD_ + lh * 8;
#pragma unroll
  for (int st = 0; st < 16; ++st) qf[st] = *(const bf16x8*)(qp + st * 16);

  f32x16 oacc[8] = {};  // O^T: d = dt*32 + (j&3)+8*(j>>2)+4*lh, q = l31
  float m_r = -3.0e38f, l_r = 0.f;
  int nkv = (t >> 1) + 1;

  {  // prologue: stage kt=0
    uint4 vst[4];
    STAGE_K(&Ks[0][0], 0);
    LOAD_V(vst, 0);
    WRITE_V(vst, 0);
  }
  __syncthreads();

  int cur = 0;
  for (int kt = 0; kt < nkv; ++kt) {
    bool more = (kt + 1 < nkv);
    uint4 vst[4];
    if (more) {
      STAGE_K(&Ks[cur ^ 1][0], kt + 1);
      LOAD_V(vst, kt + 1);
    }
    const char* Kb = (const char*)&Ks[cur][0];
    // QK^T swapped: scv[j] = S^T[k_rel=(j&3)+8*(j>>2)+4*lh][q=l31]
    int row = l31;
    int rsw = (row & 7) << 4;
    f32x16 scv = {};
    __builtin_amdgcn_s_setprio(1);
#pragma unroll
    for (int st = 0; st < 16; ++st) {
      bf16x8 kf = *(const bf16x8*)(Kb + row * 512 + ((st * 32 + lh * 16) ^ rsw));
      scv = __builtin_amdgcn_mfma_f32_32x32x16_bf16(kf, qf[st], scv, 0, 0, 0);
    }
    __builtin_amdgcn_s_setprio(0);
    int k0 = kt * 32;
    if (k0 + 31 > t * 16) {  // causal mask needed
#pragma unroll
      for (int jj = 0; jj < 16; ++jj) {
        int kg = k0 + (jj & 3) + 8 * (jj >> 2) + 4 * lh;
        if (kg > s_g) scv[jj] = -3.0e38f;
      }
    }
    float tmax = -3.0e38f;
#pragma unroll
    for (int jj = 0; jj < 16; ++jj) tmax = fmaxf(tmax, scv[jj]);
    tmax = fmaxf(tmax, __shfl_xor(tmax, 32));
    if (!__all(tmax - m_r <= 8.0f)) {  // defer-max (T13)
      float mnew = fmaxf(m_r, tmax);
      float sc = exp2f(m_r - mnew);
      l_r *= sc;
#pragma unroll
      for (int dt = 0; dt < 8; ++dt) oacc[dt] *= sc;
      m_r = mnew;
    }
    float ts = 0.f;
    unsigned cpk[8];
#pragma unroll
    for (int mi = 0; mi < 8; ++mi) {
      float p0 = exp2f(scv[2 * mi] - m_r);
      float p1 = exp2f(scv[2 * mi + 1] - m_r);
      ts += p0 + p1;
      cpk[mi] = ((unsigned)f2bf(p1) << 16) | f2bf(p0);
    }
    ts += __shfl_xor(ts, 32);
    l_r += ts;
    // in-register P^T -> B-fragments (verified): swap(A,B): A'=[A.lo,B.lo], B'=[A.hi,B.hi]
    asm volatile("v_permlane32_swap_b32 %0, %1" : "+v"(cpk[0]), "+v"(cpk[2]));
    asm volatile("v_permlane32_swap_b32 %0, %1" : "+v"(cpk[1]), "+v"(cpk[3]));
    asm volatile("v_permlane32_swap_b32 %0, %1" : "+v"(cpk[4]), "+v"(cpk[6]));
    asm volatile("v_permlane32_swap_b32 %0, %1" : "+v"(cpk[5]), "+v"(cpk[7]));
    union { unsigned u[4]; bf16x8 v; } pa, pb;
    pa.u[0] = cpk[0]; pa.u[1] = cpk[1]; pa.u[2] = cpk[2]; pa.u[3] = cpk[3];
    pb.u[0] = cpk[4]; pb.u[1] = cpk[5]; pb.u[2] = cpk[6]; pb.u[3] = cpk[7];
    // PV swapped: O^T += V^T-frag x P-frag (k-halves 0..15, 16..31 of this kt)
    int hh = kt & 1;
    __builtin_amdgcn_s_setprio(1);
#pragma unroll
    for (int dt = 0; dt < 8; ++dt) {
      int d = dt * 32 + l31;
      int swz = (d & 7) << 4;
      bf16x8 va = *(const bf16x8*)((const char*)Vs + d * 128 + ((hh * 64 + lh * 16) ^ swz));
      oacc[dt] = __builtin_amdgcn_mfma_f32_32x32x16_bf16(va, pa.v, oacc[dt], 0, 0, 0);
      bf16x8 vb2 = *(const bf16x8*)((const char*)Vs + d * 128 + ((hh * 64 + 32 + lh * 16) ^ swz));
      oacc[dt] = __builtin_amdgcn_mfma_f32_32x32x16_bf16(vb2, pb.v, oacc[dt], 0, 0, 0);
    }
    __builtin_amdgcn_s_setprio(0);
    if (more) WRITE_V(vst, kt + 1);  // other half of Vs; safe pre-barrier
    __syncthreads();                 // drains vmcnt (K gll) + lgkm (V writes)
    cur ^= 1;
  }

  // epilogue: O[qrow][d] = oacc / l  (qrow*256+d == [b*s][h*256+d] flat)
  float inv = 1.0f / l_r;
  u16* ob = Op + qrow * 256;
#pragma unroll
  for (int dt = 0; dt < 8; ++dt) {
#pragma unroll
    for (int jj = 0; jj < 4; ++jj) {
      int d0 = dt * 32 + jj * 8 + 4 * lh;
      u16 o4[4];
#pragma unroll
      for (int e = 0; e < 4; ++e) o4[e] = f2bf(oacc[dt][jj * 4 + e] * inv);
      *(ull*)(ob + d0) = *(const ull*)o4;
    }
  }
}

extern "C" void kernel_launch(void* const* d_in, const int* in_sizes, int n_in,
                              void* d_out, int out_size, void* d_ws, size_t ws_size,
                              hipStream_t stream) {
  const float* x = (const float*)d_in[0];
  const float* w_qkv = (const float*)d_in[1];
  const float* b_qkv = (const float*)d_in[2];
  const float* w_o = (const float*)d_in[3];
  const float* b_o = (const float*)d_in[4];
  const float* freqs = (const float*)d_in[5];
  // d_in[6] is the causal mask; causality is implemented directly.

  char* ws = (char*)d_ws;
  u16* xb    = (u16*)ws;                          // 33,554,432 B
  u16* wqkvT = (u16*)(ws + 33554432);             // 10,485,760 B
  u16* woT   = (u16*)(ws + 44040192);             //  8,388,608 B
  u16* qkv   = (u16*)(ws + 52428800);             // 41,943,040 B
  u16* qall  = (u16*)(ws + 94371840);             // 33,554,432 B
  u16* kbuf  = (u16*)(ws + 127926272);            //  4,194,304 B
  u16* vbuf  = (u16*)(ws + 132120576);            //  4,194,304 B
  u16* vT    = xb;    // alias: xb dead after QKV GEMM
  u16* attout = qkv;  // alias: qkv dead after rope_scatter

  cast_f32_bf16<<<2048, 256, 0, stream>>>(x, xb, (B_ * S_ * HID_) / 8);
  transpose_cast<<<dim3(QKVN / 32, HID_ / 32), dim3(32, 8), 0, stream>>>(w_qkv, wqkvT, HID_, QKVN);
  transpose_cast<<<dim3(HID_ / 32, HID_ / 32), dim3(32, 8), 0, stream>>>(w_o, woT, HID_, HID_);
  gemm_bt<false><<<dim3(64 * 20), 256, 0, stream>>>(xb, wqkvT, b_qkv, qkv, B_ * S_, QKVN, HID_);
  rope_scatter<<<2048, 256, 0, stream>>>(qkv, freqs, qall, kbuf, vbuf);
  transpose_bf16<<<dim3(HD_ / 32, S_ / 32, B_), dim3(32, 8), 0, stream>>>(vbuf, vT, S_, HD_);
  flash_attn<<<512, 256, 0, stream>>>(qall, kbuf, vT, attout);
  gemm_bt<true><<<dim3(64 * 16), 256, 0, stream>>>(attout, woT, b_o, d_out, B_ * S_, HID_, HID_);
}

// Round 7
// 483.150 us; speedup vs baseline: 1.1270x; 1.1270x over previous
//
#include <hip/hip_runtime.h>
#include <hip/hip_bf16.h>

#define B_ 4
#define S_ 2048
#define HID_ 2048
#define NH_ 8
#define HD_ 256
#define QKVN 2560

typedef unsigned short u16;
typedef unsigned long long ull;
typedef __attribute__((ext_vector_type(4))) float f32x4;
typedef __attribute__((ext_vector_type(16))) float f32x16;
typedef __attribute__((ext_vector_type(8))) short bf16x8;

__device__ __forceinline__ float bf2f(u16 u) {
  union { unsigned int i; float f; } v; v.i = ((unsigned int)u) << 16; return v.f;
}
__device__ __forceinline__ u16 f2bf(float f) {
  union { unsigned int i; float f; } v; v.f = f;
  unsigned int r = v.i + 0x7fffu + ((v.i >> 16) & 1u);
  return (u16)(r >> 16);
}

// ---------------- cast x (f32 -> bf16), 8 elems/thread ----------------
__global__ void cast_f32_bf16(const float* __restrict__ in, u16* __restrict__ out, int n8) {
  int i = blockIdx.x * blockDim.x + threadIdx.x;
  int stride = gridDim.x * blockDim.x;
  for (; i < n8; i += stride) {
    const float4* p = (const float4*)(in + (size_t)i * 8);
    float4 a = p[0], b = p[1];
    u16 o[8] = {f2bf(a.x), f2bf(a.y), f2bf(a.z), f2bf(a.w),
                f2bf(b.x), f2bf(b.y), f2bf(b.z), f2bf(b.w)};
    *(uint4*)(out + (size_t)i * 8) = *(const uint4*)o;
  }
}

// ------------- transpose + cast: in[R][C] f32 -> out[C][R] bf16 -------------
__global__ void transpose_cast(const float* __restrict__ in, u16* __restrict__ out, int R, int C) {
  __shared__ float t[32][33];
  int c0 = blockIdx.x * 32, r0 = blockIdx.y * 32;
  int tx = threadIdx.x, ty = threadIdx.y;
#pragma unroll
  for (int i = 0; i < 4; ++i)
    t[ty + i * 8][tx] = in[(size_t)(r0 + ty + i * 8) * C + c0 + tx];
  __syncthreads();
#pragma unroll
  for (int i = 0; i < 4; ++i)
    out[(size_t)(c0 + ty + i * 8) * R + r0 + tx] = f2bf(t[tx][ty + i * 8]);
}

// ------------- transpose bf16 (per-batch): in[R][C] -> out[C][R] -------------
__global__ void transpose_bf16(const u16* __restrict__ in, u16* __restrict__ out, int R, int C) {
  __shared__ u16 t[32][33];
  in += (size_t)blockIdx.z * R * C;
  out += (size_t)blockIdx.z * R * C;
  int c0 = blockIdx.x * 32, r0 = blockIdx.y * 32;
  int tx = threadIdx.x, ty = threadIdx.y;
#pragma unroll
  for (int i = 0; i < 4; ++i)
    t[ty + i * 8][tx] = in[(size_t)(r0 + ty + i * 8) * C + c0 + tx];
  __syncthreads();
#pragma unroll
  for (int i = 0; i < 4; ++i)
    out[(size_t)(c0 + ty + i * 8) * R + r0 + tx] = t[tx][ty + i * 8];
}

// ---------------- m97-style bf16 GEMM: C[M][N] = A[M][K] * BT[N][K]^T + bias ----------------
template <bool OUT_F32>
__global__ __launch_bounds__(256) void gemm_bt(const u16* __restrict__ A, const u16* __restrict__ BT,
                                               const float* __restrict__ bias, void* __restrict__ Cout,
                                               int M, int N, int K) {
  __shared__ u16 As[128 * 32];
  __shared__ u16 Bs[128 * 32];
  int nwg = gridDim.x;
  int bid = (int)blockIdx.x;
  bid = (bid & 7) * (nwg >> 3) + (bid >> 3);  // XCD swizzle (nwg % 8 == 0)
  int ntiles = N >> 7;
  int m0 = (bid / ntiles) << 7, n0 = (bid % ntiles) << 7;
  int tid = threadIdx.x, w = tid >> 6, lane = tid & 63;
  int wr = w >> 1, wc = w & 1;
  int l15 = lane & 15, lg = lane >> 4;
  f32x4 acc[4][4] = {};
  int crow = lane >> 2;
  int ccol = (lane & 3) * 8;
  for (int k0 = 0; k0 < K; k0 += 32) {
#pragma unroll
    for (int i = 0; i < 2; ++i) {
      int c = w * 2 + i;
      const u16* ga = A + (size_t)(m0 + c * 16 + crow) * K + k0 + ccol;
      const u16* gb = BT + (size_t)(n0 + c * 16 + crow) * K + k0 + ccol;
      __builtin_amdgcn_global_load_lds((const __attribute__((address_space(1))) void*)ga,
                                       (__attribute__((address_space(3))) void*)(As + c * 512), 16, 0, 0);
      __builtin_amdgcn_global_load_lds((const __attribute__((address_space(1))) void*)gb,
                                       (__attribute__((address_space(3))) void*)(Bs + c * 512), 16, 0, 0);
    }
    __syncthreads();
    bf16x8 af[4], bfr[4];
#pragma unroll
    for (int r = 0; r < 4; ++r)
      af[r] = *(const bf16x8*)&As[(wr * 64 + r * 16 + l15) * 32 + lg * 8];
#pragma unroll
    for (int c = 0; c < 4; ++c)
      bfr[c] = *(const bf16x8*)&Bs[(wc * 64 + c * 16 + l15) * 32 + lg * 8];
#pragma unroll
    for (int r = 0; r < 4; ++r)
#pragma unroll
      for (int c = 0; c < 4; ++c)
        acc[r][c] = __builtin_amdgcn_mfma_f32_16x16x32_bf16(af[r], bfr[c], acc[r][c], 0, 0, 0);
    __syncthreads();
  }
#pragma unroll
  for (int r = 0; r < 4; ++r) {
    int mrow = m0 + wr * 64 + r * 16 + lg * 4;
#pragma unroll
    for (int c = 0; c < 4; ++c) {
      int col = n0 + wc * 64 + c * 16 + l15;
      float bv = bias[col];
#pragma unroll
      for (int j = 0; j < 4; ++j) {
        float v = acc[r][c][j] + bv;
        if (OUT_F32)
          ((float*)Cout)[(size_t)(mrow + j) * N + col] = v;
        else
          ((u16*)Cout)[(size_t)(mrow + j) * N + col] = f2bf(v);
      }
    }
  }
}

// ---------------- RoPE + scatter qkv -> q_pack [b][s][h][d] / k / v (bf16) ----------------
__global__ void rope_scatter(const u16* __restrict__ qkv, const float* __restrict__ freqs,
                             u16* __restrict__ qo, u16* __restrict__ ko, u16* __restrict__ vo) {
  const int per_row = QKVN / 8;  // 320
  const int total = B_ * S_ * per_row;
  int i = blockIdx.x * blockDim.x + threadIdx.x;
  int stride = gridDim.x * blockDim.x;
  for (; i < total; i += stride) {
    int m = i / per_row;
    int n8 = (i - m * per_row) * 8;
    int b = m >> 11, s = m & 2047;
    uint4 raw = *(const uint4*)(qkv + (size_t)m * QKVN + n8);
    const u16* u = (const u16*)&raw;
    if (n8 < 2304) {
      int d = (n8 < 2048) ? (n8 & 255) : (n8 - 2048);
      float scl = (n8 < 2048) ? (0.0625f * 1.44269504f) : 1.0f;
      const float* fp = freqs + ((size_t)s * 128 + (d >> 1)) * 2;
      float4 f0 = *(const float4*)fp;
      float4 f1 = *(const float4*)(fp + 4);
      float fc[8] = {f0.x, f0.y, f0.z, f0.w, f1.x, f1.y, f1.z, f1.w};
      u16 o[8];
#pragma unroll
      for (int p = 0; p < 4; ++p) {
        float r = bf2f(u[2 * p]), im = bf2f(u[2 * p + 1]);
        float c = fc[2 * p], sn = fc[2 * p + 1];
        o[2 * p] = f2bf((r * c - im * sn) * scl);
        o[2 * p + 1] = f2bf((r * sn + im * c) * scl);
      }
      u16* dst;
      if (n8 < 2048) {
        dst = qo + (size_t)m * 2048 + n8;  // packed [b][s][h][d]
      } else {
        dst = ko + (((size_t)m) << 8) + d;
      }
      *(uint4*)dst = *(const uint4*)o;
    } else {
      int d = n8 - 2304;
      *(uint4*)(vo + (((size_t)m) << 8) + d) = raw;
    }
  }
}

// ---------------- flash attention core (R4-verified datapath) ----------------
#define STAGE_K(bufofs, kt)                                                                       \
  do {                                                                                            \
    const u16* _src0 = Kp + ((size_t)(b * S_ + (kt) * 64)) * HD_;                                 \
    _Pragma("unroll") for (int _p = 0; _p < 4; ++_p) {                                            \
      int _idx = _p * 512 + tid;                                                                  \
      int _row = _idx >> 5, _c = _idx & 31;                                                       \
      int _scol = (((_c * 16) ^ ((_row & 7) << 4)) >> 1);                                         \
      __builtin_amdgcn_global_load_lds(                                                           \
          (const __attribute__((address_space(1))) void*)(_src0 + (size_t)_row * HD_ + _scol),    \
          (__attribute__((address_space(3))) void*)(KsBase + (bufofs) + _idx * 8), 16, 0, 0);     \
    }                                                                                             \
  } while (0)

#define STAGE_V(bufofs, kt)                                                                       \
  do {                                                                                            \
    const u16* _src1 = VTp + (size_t)b * HD_ * S_ + (kt) * 64;                                    \
    _Pragma("unroll") for (int _p = 0; _p < 4; ++_p) {                                            \
      int _idx = _p * 512 + tid;                                                                  \
      int _d = _idx >> 3, _c = _idx & 7;                                                          \
      int _scol = (((_c * 16) ^ ((_d & 7) << 4)) >> 1);                                           \
      __builtin_amdgcn_global_load_lds(                                                           \
          (const __attribute__((address_space(1))) void*)(_src1 + (size_t)_d * S_ + _scol),       \
          (__attribute__((address_space(3))) void*)(VsBase + (bufofs) + _idx * 8), 16, 0, 0);     \
    }                                                                                             \
  } while (0)

// Core loop over kt in [kb, ke): updates m_r, l_r, oacc. Assumes kb < ke.
#define FLASH_SEG_BODY()                                                                          \
  STAGE_K(0, kb);                                                                                 \
  STAGE_V(0, kb);                                                                                 \
  __syncthreads();                                                                                \
  int cur = 0;                                                                                    \
  for (int kt = kb; kt < ke; ++kt) {                                                              \
    if (kt + 1 < ke) {                                                                            \
      STAGE_K((cur ^ 1) * 16384, kt + 1);                                                         \
      STAGE_V((cur ^ 1) * 16384, kt + 1);                                                         \
    }                                                                                             \
    const char* Kb = (const char*)KsBase + cur * 32768;                                           \
    const char* Vb = (const char*)VsBase + cur * 32768;                                           \
    _Pragma("unroll") for (int tau = 0; tau < 2; ++tau) {                                         \
      int k0 = kt * 64 + tau * 32;                                                                \
      if (k0 > t * 32 + 31) break;                                                                \
      f32x16 scv = {};                                                                            \
      __builtin_amdgcn_s_setprio(1);                                                              \
      _Pragma("unroll") for (int st = 0; st < 16; ++st) {                                         \
        int row = tau * 32 + l31;                                                                 \
        bf16x8 kf = *(const bf16x8*)(Kb + row * 512 + ((st * 32 + lh * 16) ^ ((row & 7) << 4)));  \
        scv = __builtin_amdgcn_mfma_f32_32x32x16_bf16(kf, qf[st], scv, 0, 0, 0);                  \
      }                                                                                           \
      __builtin_amdgcn_s_setprio(0);                                                              \
      if (k0 + 31 > t * 32) {                                                                     \
        _Pragma("unroll") for (int jj = 0; jj < 16; ++jj) {                                       \
          int kg = k0 + (jj & 3) + 8 * (jj >> 2) + 4 * lh;                                        \
          if (kg > s_g) scv[jj] = -3.0e38f;                                                       \
        }                                                                                         \
      }                                                                                           \
      float tmax = -3.0e38f;                                                                      \
      _Pragma("unroll") for (int jj = 0; jj < 16; ++jj) tmax = fmaxf(tmax, scv[jj]);              \
      tmax = fmaxf(tmax, __shfl_xor(tmax, 32));                                                   \
      if (!__all(tmax - m_r <= 8.0f)) {                                                           \
        float mnew = fmaxf(m_r, tmax);                                                            \
        float sc = exp2f(m_r - mnew);                                                             \
        l_r *= sc;                                                                                \
        _Pragma("unroll") for (int dt = 0; dt < 8; ++dt) oacc[dt] *= sc;                          \
        m_r = mnew;                                                                               \
      }                                                                                           \
      float ts = 0.f;                                                                             \
      unsigned cpk[8];                                                                            \
      _Pragma("unroll") for (int mi = 0; mi < 8; ++mi) {                                          \
        float p0 = exp2f(scv[2 * mi] - m_r);                                                      \
        float p1 = exp2f(scv[2 * mi + 1] - m_r);                                                  \
        ts += p0 + p1;                                                                            \
        cpk[mi] = ((unsigned)f2bf(p1) << 16) | f2bf(p0);                                          \
      }                                                                                           \
      ts += __shfl_xor(ts, 32);                                                                   \
      l_r += ts;                                                                                  \
      asm volatile("v_permlane32_swap_b32 %0, %1" : "+v"(cpk[0]), "+v"(cpk[2]));                  \
      asm volatile("v_permlane32_swap_b32 %0, %1" : "+v"(cpk[1]), "+v"(cpk[3]));                  \
      asm volatile("v_permlane32_swap_b32 %0, %1" : "+v"(cpk[4]), "+v"(cpk[6]));                  \
      asm volatile("v_permlane32_swap_b32 %0, %1" : "+v"(cpk[5]), "+v"(cpk[7]));                  \
      union { unsigned u[4]; bf16x8 v; } pa, pb;                                                  \
      pa.u[0] = cpk[0]; pa.u[1] = cpk[1]; pa.u[2] = cpk[2]; pa.u[3] = cpk[3];                     \
      pb.u[0] = cpk[4]; pb.u[1] = cpk[5]; pb.u[2] = cpk[6]; pb.u[3] = cpk[7];                     \
      __builtin_amdgcn_s_setprio(1);                                                              \
      _Pragma("unroll") for (int dt = 0; dt < 8; ++dt) {                                          \
        int d = dt * 32 + l31;                                                                    \
        int swz = (d & 7) << 4;                                                                   \
        bf16x8 va = *(const bf16x8*)(Vb + d * 128 + (((2 * tau) * 32 + lh * 16) ^ swz));          \
        oacc[dt] = __builtin_amdgcn_mfma_f32_32x32x16_bf16(va, pa.v, oacc[dt], 0, 0, 0);          \
        bf16x8 vb2 = *(const bf16x8*)(Vb + d * 128 + (((2 * tau + 1) * 32 + lh * 16) ^ swz));     \
        oacc[dt] = __builtin_amdgcn_mfma_f32_32x32x16_bf16(vb2, pb.v, oacc[dt], 0, 0, 0);         \
      }                                                                                           \
      __builtin_amdgcn_s_setprio(0);                                                              \
    }                                                                                             \
    __syncthreads();                                                                              \
    cur ^= 1;                                                                                     \
  }

// ---------------- R4 flash (fallback, full range per tile) ----------------
__global__ __launch_bounds__(512, 2) void flash_attn(const u16* __restrict__ Qp, const u16* __restrict__ Kp,
                                                     const u16* __restrict__ VTp, u16* __restrict__ Op) {
  __shared__ u16 Ks[2][64 * 256];
  __shared__ u16 Vs[2][256 * 64];
  int bid = (int)blockIdx.x;
  int b = bid & 3, t = bid >> 2;
  int tid = threadIdx.x;
  int w = tid >> 6, l = tid & 63;
  int l31 = l & 31, lh = l >> 5;
  int q_local = w * 32 + l31;
  size_t qrow = (size_t)b * 16384 + (size_t)t * 256 + q_local;
  int s_g = t * 32 + (q_local >> 3);
  u16* KsBase = &Ks[0][0];
  u16* VsBase = &Vs[0][0];
  bf16x8 qf[16];
  const u16* qp = Qp + qrow * HD_ + lh * 8;
#pragma unroll
  for (int st = 0; st < 16; ++st) qf[st] = *(const bf16x8*)(qp + st * 16);
  f32x16 oacc[8] = {};
  float m_r = -3.0e38f, l_r = 0.f;
  int kb = 0, ke = t / 2 + 1;
  FLASH_SEG_BODY();
  float inv = 1.0f / l_r;
  u16* ob = Op + qrow * 256;
#pragma unroll
  for (int dt = 0; dt < 8; ++dt) {
#pragma unroll
    for (int jj = 0; jj < 4; ++jj) {
      int d0 = dt * 32 + jj * 8 + 4 * lh;
      u16 o4[4];
#pragma unroll
      for (int e = 0; e < 4; ++e) o4[e] = f2bf(oacc[dt][jj * 4 + e] * inv);
      *(ull*)(ob + d0) = *(const ull*)o4;
    }
  }
}

// ---------------- split-kv flash: block j does (tile j, part0) + (tile 63-j, part1) ----------------
// Every block runs 16-17 kt (balanced). Partials: part0 -> P0 (normalized O bf16) + ml0;
// part1 -> attout slot + ml1. combine_parts merges.
__global__ __launch_bounds__(512, 2) void flash_attn_split(const u16* __restrict__ Qp, const u16* __restrict__ Kp,
                                                           const u16* __restrict__ VTp, u16* __restrict__ P0,
                                                           float* __restrict__ ml0, float* __restrict__ ml1,
                                                           u16* __restrict__ Op) {
  __shared__ u16 Ks[2][64 * 256];
  __shared__ u16 Vs[2][256 * 64];
  int bid = (int)blockIdx.x;
  // XCD map: xcd = bid&7 -> b = (bid&7)>>1 (one b per XCD pair, K/V 2MB fits L2)
  int b = (bid & 7) >> 1;
  int j = ((bid & 1) << 5) + (bid >> 3);  // 0..63
  int tid = threadIdx.x;
  int w = tid >> 6, l = tid & 63;
  int l31 = l & 31, lh = l >> 5;
  int q_local = w * 32 + l31;
  u16* KsBase = &Ks[0][0];
  u16* VsBase = &Vs[0][0];

  for (int seg = 0; seg < 2; ++seg) {
    int t = seg ? (63 - j) : j;
    int nkv = (t >> 1) + 1;
    int half = (nkv + 1) >> 1;
    int kb = seg ? half : 0;
    int ke = seg ? nkv : half;
    size_t qrow = (size_t)b * 16384 + (size_t)t * 256 + q_local;
    int s_g = t * 32 + (q_local >> 3);
    float* mlbuf = seg ? ml1 : ml0;
    if (kb >= ke) {  // uniform across block (t=0,1 part1 only)
      if (lh == 0) { mlbuf[qrow * 2] = -3.0e38f; mlbuf[qrow * 2 + 1] = 0.f; }
      continue;
    }
    bf16x8 qf[16];
    const u16* qp = Qp + qrow * HD_ + lh * 8;
#pragma unroll
    for (int st = 0; st < 16; ++st) qf[st] = *(const bf16x8*)(qp + st * 16);
    f32x16 oacc[8] = {};
    float m_r = -3.0e38f, l_r = 0.f;
    FLASH_SEG_BODY();
    float inv = 1.0f / l_r;
    u16* ob = (seg ? Op : P0) + qrow * 256;
#pragma unroll
    for (int dt = 0; dt < 8; ++dt) {
#pragma unroll
      for (int jj = 0; jj < 4; ++jj) {
        int d0 = dt * 32 + jj * 8 + 4 * lh;
        u16 o4[4];
#pragma unroll
        for (int e = 0; e < 4; ++e) o4[e] = f2bf(oacc[dt][jj * 4 + e] * inv);
        *(ull*)(ob + d0) = *(const ull*)o4;
      }
    }
    if (lh == 0) { mlbuf[qrow * 2] = m_r; mlbuf[qrow * 2 + 1] = l_r; }
  }
}

// ---------------- combine: O = (w0*O0 + w1*O1) / (w0+w1), wi = li * 2^(mi - M) ----------------
__global__ __launch_bounds__(256) void combine_parts(const u16* __restrict__ P0, const float* __restrict__ ml0,
                                                     const float* __restrict__ ml1, u16* __restrict__ O) {
  int r = blockIdx.x * 256 + threadIdx.x;  // q-row 0..65535
  float m0 = ml0[(size_t)r * 2], l0 = ml0[(size_t)r * 2 + 1];
  float m1 = ml1[(size_t)r * 2], l1 = ml1[(size_t)r * 2 + 1];
  float M = fmaxf(m0, m1);
  float w0 = l0 * exp2f(m0 - M), w1 = l1 * exp2f(m1 - M);
  float inv = 1.0f / (w0 + w1);
  w0 *= inv; w1 *= inv;
  const u16* p0 = P0 + (size_t)r * 256;
  u16* p1 = O + (size_t)r * 256;
#pragma unroll 4
  for (int c = 0; c < 32; ++c) {
    uint4 a = *(const uint4*)(p0 + c * 8);
    uint4 bq = *(const uint4*)(p1 + c * 8);
    const u16* ua = (const u16*)&a;
    const u16* ub = (const u16*)&bq;
    u16 o[8];
#pragma unroll
    for (int e = 0; e < 8; ++e) o[e] = f2bf(w0 * bf2f(ua[e]) + w1 * bf2f(ub[e]));
    *(uint4*)(p1 + c * 8) = *(const uint4*)o;
  }
}

extern "C" void kernel_launch(void* const* d_in, const int* in_sizes, int n_in,
                              void* d_out, int out_size, void* d_ws, size_t ws_size,
                              hipStream_t stream) {
  const float* x = (const float*)d_in[0];
  const float* w_qkv = (const float*)d_in[1];
  const float* b_qkv = (const float*)d_in[2];
  const float* w_o = (const float*)d_in[3];
  const float* b_o = (const float*)d_in[4];
  const float* freqs = (const float*)d_in[5];
  // d_in[6] is the causal mask; causality is implemented directly.

  char* ws = (char*)d_ws;
  u16* xb    = (u16*)ws;                          // 33,554,432 B
  u16* wqkvT = (u16*)(ws + 33554432);             // 10,485,760 B
  u16* woT   = (u16*)(ws + 44040192);             //  8,388,608 B
  u16* qkv   = (u16*)(ws + 52428800);             // 41,943,040 B
  u16* qall  = (u16*)(ws + 94371840);             // 33,554,432 B
  u16* kbuf  = (u16*)(ws + 127926272);            //  4,194,304 B
  u16* vbuf  = (u16*)(ws + 132120576);            //  4,194,304 B
  u16* part0 = (u16*)(ws + 136314880);            // 33,554,432 B (split path only)
  float* ml0 = (float*)(ws + 169869312);          //    524,288 B
  float* ml1 = (float*)(ws + 170393600);          //    524,288 B  -> need 170,917,888
  u16* vT    = xb;    // alias: xb dead after QKV GEMM
  u16* attout = qkv;  // alias: qkv dead after rope_scatter

  bool split = (ws_size >= 170917888ULL);

  cast_f32_bf16<<<2048, 256, 0, stream>>>(x, xb, (B_ * S_ * HID_) / 8);
  transpose_cast<<<dim3(QKVN / 32, HID_ / 32), dim3(32, 8), 0, stream>>>(w_qkv, wqkvT, HID_, QKVN);
  transpose_cast<<<dim3(HID_ / 32, HID_ / 32), dim3(32, 8), 0, stream>>>(w_o, woT, HID_, HID_);
  gemm_bt<false><<<dim3(64 * 20), 256, 0, stream>>>(xb, wqkvT, b_qkv, qkv, B_ * S_, QKVN, HID_);
  rope_scatter<<<2048, 256, 0, stream>>>(qkv, freqs, qall, kbuf, vbuf);
  transpose_bf16<<<dim3(HD_ / 32, S_ / 32, B_), dim3(32, 8), 0, stream>>>(vbuf, vT, S_, HD_);
  if (split) {
    flash_attn_split<<<256, 512, 0, stream>>>(qall, kbuf, vT, part0, ml0, ml1, attout);
    combine_parts<<<256, 256, 0, stream>>>(part0, ml0, ml1, attout);
  } else {
    flash_attn<<<256, 512, 0, stream>>>(qall, kbuf, vT, attout);
  }
  gemm_bt<true><<<dim3(64 * 16), 256, 0, stream>>>(attout, woT, b_o, d_out, B_ * S_, HID_, HID_);
}

// Round 8
// 421.667 us; speedup vs baseline: 1.2913x; 1.1458x over previous
//
#include <hip/hip_runtime.h>
#include <hip/hip_bf16.h>

#define B_ 4
#define S_ 2048
#define HID_ 2048
#define NH_ 8
#define HD_ 256
#define QKVN 2560

typedef unsigned short u16;
typedef unsigned long long ull;
typedef __attribute__((ext_vector_type(4))) float f32x4;
typedef __attribute__((ext_vector_type(16))) float f32x16;
typedef __attribute__((ext_vector_type(8))) short bf16x8;

__device__ __forceinline__ float bf2f(u16 u) {
  union { unsigned int i; float f; } v; v.i = ((unsigned int)u) << 16; return v.f;
}
__device__ __forceinline__ u16 f2bf(float f) {
  union { unsigned int i; float f; } v; v.f = f;
  unsigned int r = v.i + 0x7fffu + ((v.i >> 16) & 1u);
  return (u16)(r >> 16);
}

// ---------------- cast x (f32 -> bf16), 8 elems/thread ----------------
__global__ void cast_f32_bf16(const float* __restrict__ in, u16* __restrict__ out, int n8) {
  int i = blockIdx.x * blockDim.x + threadIdx.x;
  int stride = gridDim.x * blockDim.x;
  for (; i < n8; i += stride) {
    const float4* p = (const float4*)(in + (size_t)i * 8);
    float4 a = p[0], b = p[1];
    u16 o[8] = {f2bf(a.x), f2bf(a.y), f2bf(a.z), f2bf(a.w),
                f2bf(b.x), f2bf(b.y), f2bf(b.z), f2bf(b.w)};
    *(uint4*)(out + (size_t)i * 8) = *(const uint4*)o;
  }
}

// ------------- transpose + cast: in[R][C] f32 -> out[C][R] bf16 -------------
__global__ void transpose_cast(const float* __restrict__ in, u16* __restrict__ out, int R, int C) {
  __shared__ float t[32][33];
  int c0 = blockIdx.x * 32, r0 = blockIdx.y * 32;
  int tx = threadIdx.x, ty = threadIdx.y;
#pragma unroll
  for (int i = 0; i < 4; ++i)
    t[ty + i * 8][tx] = in[(size_t)(r0 + ty + i * 8) * C + c0 + tx];
  __syncthreads();
#pragma unroll
  for (int i = 0; i < 4; ++i)
    out[(size_t)(c0 + ty + i * 8) * R + r0 + tx] = f2bf(t[tx][ty + i * 8]);
}

// ------------- transpose bf16 (per-batch): in[R][C] -> out[C][R] -------------
__global__ void transpose_bf16(const u16* __restrict__ in, u16* __restrict__ out, int R, int C) {
  __shared__ u16 t[32][33];
  in += (size_t)blockIdx.z * R * C;
  out += (size_t)blockIdx.z * R * C;
  int c0 = blockIdx.x * 32, r0 = blockIdx.y * 32;
  int tx = threadIdx.x, ty = threadIdx.y;
#pragma unroll
  for (int i = 0; i < 4; ++i)
    t[ty + i * 8][tx] = in[(size_t)(r0 + ty + i * 8) * C + c0 + tx];
  __syncthreads();
#pragma unroll
  for (int i = 0; i < 4; ++i)
    out[(size_t)(c0 + ty + i * 8) * R + r0 + tx] = t[tx][ty + i * 8];
}

// ---------------- m97-style bf16 GEMM: C[M][N] = A[M][K] * BT[N][K]^T + bias ----------------
template <bool OUT_F32>
__global__ __launch_bounds__(256) void gemm_bt(const u16* __restrict__ A, const u16* __restrict__ BT,
                                               const float* __restrict__ bias, void* __restrict__ Cout,
                                               int M, int N, int K) {
  __shared__ u16 As[128 * 32];
  __shared__ u16 Bs[128 * 32];
  int nwg = gridDim.x;
  int bid = (int)blockIdx.x;
  bid = (bid & 7) * (nwg >> 3) + (bid >> 3);  // XCD swizzle (nwg % 8 == 0)
  int ntiles = N >> 7;
  int m0 = (bid / ntiles) << 7, n0 = (bid % ntiles) << 7;
  int tid = threadIdx.x, w = tid >> 6, lane = tid & 63;
  int wr = w >> 1, wc = w & 1;
  int l15 = lane & 15, lg = lane >> 4;
  f32x4 acc[4][4] = {};
  int crow = lane >> 2;
  int ccol = (lane & 3) * 8;
  for (int k0 = 0; k0 < K; k0 += 32) {
#pragma unroll
    for (int i = 0; i < 2; ++i) {
      int c = w * 2 + i;
      const u16* ga = A + (size_t)(m0 + c * 16 + crow) * K + k0 + ccol;
      const u16* gb = BT + (size_t)(n0 + c * 16 + crow) * K + k0 + ccol;
      __builtin_amdgcn_global_load_lds((const __attribute__((address_space(1))) void*)ga,
                                       (__attribute__((address_space(3))) void*)(As + c * 512), 16, 0, 0);
      __builtin_amdgcn_global_load_lds((const __attribute__((address_space(1))) void*)gb,
                                       (__attribute__((address_space(3))) void*)(Bs + c * 512), 16, 0, 0);
    }
    __syncthreads();
    bf16x8 af[4], bfr[4];
#pragma unroll
    for (int r = 0; r < 4; ++r)
      af[r] = *(const bf16x8*)&As[(wr * 64 + r * 16 + l15) * 32 + lg * 8];
#pragma unroll
    for (int c = 0; c < 4; ++c)
      bfr[c] = *(const bf16x8*)&Bs[(wc * 64 + c * 16 + l15) * 32 + lg * 8];
#pragma unroll
    for (int r = 0; r < 4; ++r)
#pragma unroll
      for (int c = 0; c < 4; ++c)
        acc[r][c] = __builtin_amdgcn_mfma_f32_16x16x32_bf16(af[r], bfr[c], acc[r][c], 0, 0, 0);
    __syncthreads();
  }
#pragma unroll
  for (int r = 0; r < 4; ++r) {
    int mrow = m0 + wr * 64 + r * 16 + lg * 4;
#pragma unroll
    for (int c = 0; c < 4; ++c) {
      int col = n0 + wc * 64 + c * 16 + l15;
      float bv = bias[col];
#pragma unroll
      for (int j = 0; j < 4; ++j) {
        float v = acc[r][c][j] + bv;
        if (OUT_F32)
          ((float*)Cout)[(size_t)(mrow + j) * N + col] = v;
        else
          ((u16*)Cout)[(size_t)(mrow + j) * N + col] = f2bf(v);
      }
    }
  }
}

// ---------------- RoPE + scatter qkv -> q_pack [b][s][h][d] / k / v (bf16) ----------------
__global__ void rope_scatter(const u16* __restrict__ qkv, const float* __restrict__ freqs,
                             u16* __restrict__ qo, u16* __restrict__ ko, u16* __restrict__ vo) {
  const int per_row = QKVN / 8;  // 320
  const int total = B_ * S_ * per_row;
  int i = blockIdx.x * blockDim.x + threadIdx.x;
  int stride = gridDim.x * blockDim.x;
  for (; i < total; i += stride) {
    int m = i / per_row;
    int n8 = (i - m * per_row) * 8;
    int b = m >> 11, s = m & 2047;
    uint4 raw = *(const uint4*)(qkv + (size_t)m * QKVN + n8);
    const u16* u = (const u16*)&raw;
    if (n8 < 2304) {
      int d = (n8 < 2048) ? (n8 & 255) : (n8 - 2048);
      float scl = (n8 < 2048) ? (0.0625f * 1.44269504f) : 1.0f;
      const float* fp = freqs + ((size_t)s * 128 + (d >> 1)) * 2;
      float4 f0 = *(const float4*)fp;
      float4 f1 = *(const float4*)(fp + 4);
      float fc[8] = {f0.x, f0.y, f0.z, f0.w, f1.x, f1.y, f1.z, f1.w};
      u16 o[8];
#pragma unroll
      for (int p = 0; p < 4; ++p) {
        float r = bf2f(u[2 * p]), im = bf2f(u[2 * p + 1]);
        float c = fc[2 * p], sn = fc[2 * p + 1];
        o[2 * p] = f2bf((r * c - im * sn) * scl);
        o[2 * p + 1] = f2bf((r * sn + im * c) * scl);
      }
      u16* dst;
      if (n8 < 2048) {
        dst = qo + (size_t)m * 2048 + n8;  // packed [b][s][h][d]
      } else {
        dst = ko + (((size_t)m) << 8) + d;
      }
      *(uint4*)dst = *(const uint4*)o;
    } else {
      int d = n8 - 2304;
      *(uint4*)(vo + (((size_t)m) << 8) + d) = raw;
    }
  }
}

// ---------------- flash attention core ----------------
// K LDS: [64 rows][512B], granule ^= row&31  -> conflict-free ds_read_b128.
// V LDS: paired rows [128 r][256B] (r = d>>1, granule = (d&1)*8 + chunk) with
//        granule ^= r&15 -> uniform bank coverage (conflict-free).
// Both staged by global_load_lds with linear LDS dest + inverse-swizzled SOURCE (rule 21).

#define STAGE_K(bufofs, kt)                                                                       \
  do {                                                                                            \
    _Pragma("unroll") for (int _p = 0; _p < 4; ++_p) {                                            \
      int _idx = _p * 512 + tid;                                                                  \
      int _row = _idx >> 5, _c = _idx & 31;                                                       \
      const u16* _src = Kp + ((size_t)(b * S_ + (kt) * 64 + _row)) * HD_ +                        \
                        ((_c ^ (_row & 31)) * 8);                                                 \
      __builtin_amdgcn_global_load_lds(                                                           \
          (const __attribute__((address_space(1))) void*)_src,                                    \
          (__attribute__((address_space(3))) void*)(KsBase + (bufofs) + _idx * 8), 16, 0, 0);     \
    }                                                                                             \
  } while (0)

#define STAGE_V(bufofs, kt)                                                                       \
  do {                                                                                            \
    _Pragma("unroll") for (int _p = 0; _p < 4; ++_p) {                                            \
      int _idx = _p * 512 + tid;                                                                  \
      int _r = _idx >> 4, _gp = _idx & 15;                                                        \
      int _g = _gp ^ (_r & 15);                                                                   \
      int _d = _r * 2 + (_g >> 3), _c = _g & 7;                                                   \
      const u16* _src = VTp + ((size_t)(b * 256 + _d)) * S_ + (kt) * 64 + _c * 8;                 \
      __builtin_amdgcn_global_load_lds(                                                           \
          (const __attribute__((address_space(1))) void*)_src,                                    \
          (__attribute__((address_space(3))) void*)(VsBase + (bufofs) + _idx * 8), 16, 0, 0);     \
    }                                                                                             \
  } while (0)

// Core loop over kt in [kb, ke): updates m_r, l_r, oacc. Assumes kb < ke.
#define FLASH_SEG_BODY()                                                                          \
  STAGE_K(0, kb);                                                                                 \
  STAGE_V(0, kb);                                                                                 \
  __syncthreads();                                                                                \
  int cur = 0;                                                                                    \
  for (int kt = kb; kt < ke; ++kt) {                                                              \
    if (kt + 1 < ke) {                                                                            \
      STAGE_K((cur ^ 1) * 16384, kt + 1);                                                         \
      STAGE_V((cur ^ 1) * 16384, kt + 1);                                                         \
    }                                                                                             \
    const char* Kb = (const char*)(KsBase + cur * 16384);                                         \
    const char* Vb = (const char*)(VsBase + cur * 16384);                                         \
    _Pragma("unroll") for (int tau = 0; tau < 2; ++tau) {                                         \
      int k0 = kt * 64 + tau * 32;                                                                \
      if (k0 > t * 32 + 31) break;                                                                \
      int row = tau * 32 + l31;                                                                   \
      f32x16 scv = {};                                                                            \
      __builtin_amdgcn_s_setprio(1);                                                              \
      _Pragma("unroll") for (int st = 0; st < 16; ++st) {                                         \
        bf16x8 kf = *(const bf16x8*)(Kb + row * 512 + (((st * 2 + lh) ^ l31) << 4));              \
        scv = __builtin_amdgcn_mfma_f32_32x32x16_bf16(kf, qf[st], scv, 0, 0, 0);                  \
      }                                                                                           \
      __builtin_amdgcn_s_setprio(0);                                                              \
      if (k0 + 31 > t * 32) {                                                                     \
        _Pragma("unroll") for (int jj = 0; jj < 16; ++jj) {                                       \
          int kg = k0 + (jj & 3) + 8 * (jj >> 2) + 4 * lh;                                        \
          if (kg > s_g) scv[jj] = -3.0e38f;                                                       \
        }                                                                                         \
      }                                                                                           \
      float tmax = -3.0e38f;                                                                      \
      _Pragma("unroll") for (int jj = 0; jj < 16; ++jj) tmax = fmaxf(tmax, scv[jj]);              \
      tmax = fmaxf(tmax, __shfl_xor(tmax, 32));                                                   \
      if (!__all(tmax - m_r <= 8.0f)) {                                                           \
        float mnew = fmaxf(m_r, tmax);                                                            \
        float sc = exp2f(m_r - mnew);                                                             \
        l_r *= sc;                                                                                \
        _Pragma("unroll") for (int dt = 0; dt < 8; ++dt) oacc[dt] *= sc;                          \
        m_r = mnew;                                                                               \
      }                                                                                           \
      float ts = 0.f;                                                                             \
      unsigned cpk[8];                                                                            \
      _Pragma("unroll") for (int mi = 0; mi < 8; ++mi) {                                          \
        float p0 = exp2f(scv[2 * mi] - m_r);                                                      \
        float p1 = exp2f(scv[2 * mi + 1] - m_r);                                                  \
        ts += p0 + p1;                                                                            \
        cpk[mi] = ((unsigned)f2bf(p1) << 16) | f2bf(p0);                                          \
      }                                                                                           \
      ts += __shfl_xor(ts, 32);                                                                   \
      l_r += ts;                                                                                  \
      asm volatile("v_permlane32_swap_b32 %0, %1" : "+v"(cpk[0]), "+v"(cpk[2]));                  \
      asm volatile("v_permlane32_swap_b32 %0, %1" : "+v"(cpk[1]), "+v"(cpk[3]));                  \
      asm volatile("v_permlane32_swap_b32 %0, %1" : "+v"(cpk[4]), "+v"(cpk[6]));                  \
      asm volatile("v_permlane32_swap_b32 %0, %1" : "+v"(cpk[5]), "+v"(cpk[7]));                  \
      union { unsigned u[4]; bf16x8 v; } pa, pb;                                                  \
      pa.u[0] = cpk[0]; pa.u[1] = cpk[1]; pa.u[2] = cpk[2]; pa.u[3] = cpk[3];                     \
      pb.u[0] = cpk[4]; pb.u[1] = cpk[5]; pb.u[2] = cpk[6]; pb.u[3] = cpk[7];                     \
      __builtin_amdgcn_s_setprio(1);                                                              \
      _Pragma("unroll") for (int dt = 0; dt < 8; ++dt) {                                          \
        int d = dt * 32 + l31;                                                                    \
        int rr = d >> 1;                                                                          \
        int gb = (d & 1) * 8 + tau * 4;                                                           \
        int rx = (rr & 15) << 4;                                                                  \
        bf16x8 va = *(const bf16x8*)(Vb + rr * 256 + (((gb + lh) << 4) ^ rx));                    \
        oacc[dt] = __builtin_amdgcn_mfma_f32_32x32x16_bf16(va, pa.v, oacc[dt], 0, 0, 0);          \
        bf16x8 vb2 = *(const bf16x8*)(Vb + rr * 256 + (((gb + 2 + lh) << 4) ^ rx));               \
        oacc[dt] = __builtin_amdgcn_mfma_f32_32x32x16_bf16(vb2, pb.v, oacc[dt], 0, 0, 0);         \
      }                                                                                           \
      __builtin_amdgcn_s_setprio(0);                                                              \
    }                                                                                             \
    __syncthreads();                                                                              \
    cur ^= 1;                                                                                     \
  }

// ---------------- fallback flash (full range per tile) ----------------
__global__ __launch_bounds__(512, 2) void flash_attn(const u16* __restrict__ Qp, const u16* __restrict__ Kp,
                                                     const u16* __restrict__ VTp, u16* __restrict__ Op) {
  __shared__ u16 Ks[2][64 * 256];
  __shared__ u16 Vs[2][128 * 128];
  int bid = (int)blockIdx.x;
  int b = bid & 3, t = bid >> 2;
  int tid = threadIdx.x;
  int w = tid >> 6, l = tid & 63;
  int l31 = l & 31, lh = l >> 5;
  int q_local = w * 32 + l31;
  size_t qrow = (size_t)b * 16384 + (size_t)t * 256 + q_local;
  int s_g = t * 32 + (q_local >> 3);
  u16* KsBase = &Ks[0][0];
  u16* VsBase = &Vs[0][0];
  bf16x8 qf[16];
  const u16* qp = Qp + qrow * HD_ + lh * 8;
#pragma unroll
  for (int st = 0; st < 16; ++st) qf[st] = *(const bf16x8*)(qp + st * 16);
  f32x16 oacc[8] = {};
  float m_r = -3.0e38f, l_r = 0.f;
  int kb = 0, ke = t / 2 + 1;
  FLASH_SEG_BODY();
  float inv = 1.0f / l_r;
  u16* ob = Op + qrow * 256;
#pragma unroll
  for (int dt = 0; dt < 8; ++dt) {
#pragma unroll
    for (int jj = 0; jj < 4; ++jj) {
      int d0 = dt * 32 + jj * 8 + 4 * lh;
      u16 o4[4];
#pragma unroll
      for (int e = 0; e < 4; ++e) o4[e] = f2bf(oacc[dt][jj * 4 + e] * inv);
      *(ull*)(ob + d0) = *(const ull*)o4;
    }
  }
}

// ---------------- split-kv flash: block j does (tile j, part0) + (tile 63-j, part1) ----------------
__global__ __launch_bounds__(512, 2) void flash_attn_split(const u16* __restrict__ Qp, const u16* __restrict__ Kp,
                                                           const u16* __restrict__ VTp, u16* __restrict__ P0,
                                                           float* __restrict__ ml0, float* __restrict__ ml1,
                                                           u16* __restrict__ Op) {
  __shared__ u16 Ks[2][64 * 256];
  __shared__ u16 Vs[2][128 * 128];
  int bid = (int)blockIdx.x;
  // XCD map: xcd = bid&7 -> b = (bid&7)>>1 (one b per XCD pair, K/V 2MB fits L2)
  int b = (bid & 7) >> 1;
  int j = ((bid & 1) << 5) + (bid >> 3);  // 0..63
  int tid = threadIdx.x;
  int w = tid >> 6, l = tid & 63;
  int l31 = l & 31, lh = l >> 5;
  int q_local = w * 32 + l31;
  u16* KsBase = &Ks[0][0];
  u16* VsBase = &Vs[0][0];

  for (int seg = 0; seg < 2; ++seg) {
    int t = seg ? (63 - j) : j;
    int nkv = (t >> 1) + 1;
    int half = (nkv + 1) >> 1;
    int kb = seg ? half : 0;
    int ke = seg ? nkv : half;
    size_t qrow = (size_t)b * 16384 + (size_t)t * 256 + q_local;
    int s_g = t * 32 + (q_local >> 3);
    float* mlbuf = seg ? ml1 : ml0;
    if (kb >= ke) {  // uniform across block (t=0,1 part1 only)
      if (lh == 0) { mlbuf[qrow * 2] = -3.0e38f; mlbuf[qrow * 2 + 1] = 0.f; }
      continue;
    }
    bf16x8 qf[16];
    const u16* qp = Qp + qrow * HD_ + lh * 8;
#pragma unroll
    for (int st = 0; st < 16; ++st) qf[st] = *(const bf16x8*)(qp + st * 16);
    f32x16 oacc[8] = {};
    float m_r = -3.0e38f, l_r = 0.f;
    FLASH_SEG_BODY();
    float inv = 1.0f / l_r;
    u16* ob = (seg ? Op : P0) + qrow * 256;
#pragma unroll
    for (int dt = 0; dt < 8; ++dt) {
#pragma unroll
      for (int jj = 0; jj < 4; ++jj) {
        int d0 = dt * 32 + jj * 8 + 4 * lh;
        u16 o4[4];
#pragma unroll
        for (int e = 0; e < 4; ++e) o4[e] = f2bf(oacc[dt][jj * 4 + e] * inv);
        *(ull*)(ob + d0) = *(const ull*)o4;
      }
    }
    if (lh == 0) { mlbuf[qrow * 2] = m_r; mlbuf[qrow * 2 + 1] = l_r; }
  }
}

// ---------------- combine (coalesced): thread = (row, 16B col chunk) ----------------
__global__ __launch_bounds__(256) void combine_parts(const u16* __restrict__ P0, const float* __restrict__ ml0,
                                                     const float* __restrict__ ml1, u16* __restrict__ O) {
  int idx = blockIdx.x * 256 + threadIdx.x;  // 65536 rows * 32 chunks
  int r = idx >> 5;
  int c = (idx & 31) * 8;
  float m0 = ml0[(size_t)r * 2], l0 = ml0[(size_t)r * 2 + 1];
  float m1 = ml1[(size_t)r * 2], l1 = ml1[(size_t)r * 2 + 1];
  float M = fmaxf(m0, m1);
  float w0 = l0 * exp2f(m0 - M), w1 = l1 * exp2f(m1 - M);
  float inv = 1.0f / (w0 + w1);
  w0 *= inv; w1 *= inv;
  uint4 a = *(const uint4*)(P0 + (size_t)r * 256 + c);
  uint4 bq = *(const uint4*)(O + (size_t)r * 256 + c);
  const u16* ua = (const u16*)&a;
  const u16* ub = (const u16*)&bq;
  u16 o[8];
#pragma unroll
  for (int e = 0; e < 8; ++e) o[e] = f2bf(w0 * bf2f(ua[e]) + w1 * bf2f(ub[e]));
  *(uint4*)(O + (size_t)r * 256 + c) = *(const uint4*)o;
}

extern "C" void kernel_launch(void* const* d_in, const int* in_sizes, int n_in,
                              void* d_out, int out_size, void* d_ws, size_t ws_size,
                              hipStream_t stream) {
  const float* x = (const float*)d_in[0];
  const float* w_qkv = (const float*)d_in[1];
  const float* b_qkv = (const float*)d_in[2];
  const float* w_o = (const float*)d_in[3];
  const float* b_o = (const float*)d_in[4];
  const float* freqs = (const float*)d_in[5];
  // d_in[6] is the causal mask; causality is implemented directly.

  char* ws = (char*)d_ws;
  u16* xb    = (u16*)ws;                          // 33,554,432 B
  u16* wqkvT = (u16*)(ws + 33554432);             // 10,485,760 B
  u16* woT   = (u16*)(ws + 44040192);             //  8,388,608 B
  u16* qkv   = (u16*)(ws + 52428800);             // 41,943,040 B
  u16* qall  = (u16*)(ws + 94371840);             // 33,554,432 B
  u16* kbuf  = (u16*)(ws + 127926272);            //  4,194,304 B
  u16* vbuf  = (u16*)(ws + 132120576);            //  4,194,304 B
  u16* part0 = (u16*)(ws + 136314880);            // 33,554,432 B (split path only)
  float* ml0 = (float*)(ws + 169869312);          //    524,288 B
  float* ml1 = (float*)(ws + 170393600);          //    524,288 B  -> need 170,917,888
  u16* vT    = xb;    // alias: xb dead after QKV GEMM
  u16* attout = qkv;  // alias: qkv dead after rope_scatter

  bool split = (ws_size >= 170917888ULL);

  cast_f32_bf16<<<2048, 256, 0, stream>>>(x, xb, (B_ * S_ * HID_) / 8);
  transpose_cast<<<dim3(QKVN / 32, HID_ / 32), dim3(32, 8), 0, stream>>>(w_qkv, wqkvT, HID_, QKVN);
  transpose_cast<<<dim3(HID_ / 32, HID_ / 32), dim3(32, 8), 0, stream>>>(w_o, woT, HID_, HID_);
  gemm_bt<false><<<dim3(64 * 20), 256, 0, stream>>>(xb, wqkvT, b_qkv, qkv, B_ * S_, QKVN, HID_);
  rope_scatter<<<2048, 256, 0, stream>>>(qkv, freqs, qall, kbuf, vbuf);
  transpose_bf16<<<dim3(HD_ / 32, S_ / 32, B_), dim3(32, 8), 0, stream>>>(vbuf, vT, S_, HD_);
  if (split) {
    flash_attn_split<<<256, 512, 0, stream>>>(qall, kbuf, vT, part0, ml0, ml1, attout);
    combine_parts<<<8192, 256, 0, stream>>>(part0, ml0, ml1, attout);
  } else {
    flash_attn<<<256, 512, 0, stream>>>(qall, kbuf, vT, attout);
  }
  gemm_bt<true><<<dim3(64 * 16), 256, 0, stream>>>(attout, woT, b_o, d_out, B_ * S_, HID_, HID_);
}

// Round 10
// 398.042 us; speedup vs baseline: 1.3680x; 1.0594x over previous
//
#include <hip/hip_runtime.h>
#include <hip/hip_bf16.h>

#define B_ 4
#define S_ 2048
#define HID_ 2048
#define NH_ 8
#define HD_ 256
#define QKVN 2560

typedef unsigned short u16;
typedef unsigned long long ull;
typedef __attribute__((ext_vector_type(4))) float f32x4;
typedef __attribute__((ext_vector_type(16))) float f32x16;
typedef __attribute__((ext_vector_type(8))) short bf16x8;

__device__ __forceinline__ float bf2f(u16 u) {
  union { unsigned int i; float f; } v; v.i = ((unsigned int)u) << 16; return v.f;
}
__device__ __forceinline__ u16 f2bf(float f) {
  union { unsigned int i; float f; } v; v.f = f;
  unsigned int r = v.i + 0x7fffu + ((v.i >> 16) & 1u);
  return (u16)(r >> 16);
}

// ---------------- cast x (f32 -> bf16), 8 elems/thread ----------------
__global__ void cast_f32_bf16(const float* __restrict__ in, u16* __restrict__ out, int n8) {
  int i = blockIdx.x * blockDim.x + threadIdx.x;
  int stride = gridDim.x * blockDim.x;
  for (; i < n8; i += stride) {
    const float4* p = (const float4*)(in + (size_t)i * 8);
    float4 a = p[0], b = p[1];
    u16 o[8] = {f2bf(a.x), f2bf(a.y), f2bf(a.z), f2bf(a.w),
                f2bf(b.x), f2bf(b.y), f2bf(b.z), f2bf(b.w)};
    *(uint4*)(out + (size_t)i * 8) = *(const uint4*)o;
  }
}

// ------------- transpose + cast: in[R][C] f32 -> out[C][R] bf16 -------------
__global__ void transpose_cast(const float* __restrict__ in, u16* __restrict__ out, int R, int C) {
  __shared__ float t[32][33];
  int c0 = blockIdx.x * 32, r0 = blockIdx.y * 32;
  int tx = threadIdx.x, ty = threadIdx.y;
#pragma unroll
  for (int i = 0; i < 4; ++i)
    t[ty + i * 8][tx] = in[(size_t)(r0 + ty + i * 8) * C + c0 + tx];
  __syncthreads();
#pragma unroll
  for (int i = 0; i < 4; ++i)
    out[(size_t)(c0 + ty + i * 8) * R + r0 + tx] = f2bf(t[tx][ty + i * 8]);
}

// ------------- transpose bf16 (per-batch): in[R][C] -> out[C][R] -------------
__global__ void transpose_bf16(const u16* __restrict__ in, u16* __restrict__ out, int R, int C) {
  __shared__ u16 t[32][33];
  in += (size_t)blockIdx.z * R * C;
  out += (size_t)blockIdx.z * R * C;
  int c0 = blockIdx.x * 32, r0 = blockIdx.y * 32;
  int tx = threadIdx.x, ty = threadIdx.y;
#pragma unroll
  for (int i = 0; i < 4; ++i)
    t[ty + i * 8][tx] = in[(size_t)(r0 + ty + i * 8) * C + c0 + tx];
  __syncthreads();
#pragma unroll
  for (int i = 0; i < 4; ++i)
    out[(size_t)(c0 + ty + i * 8) * R + r0 + tx] = t[tx][ty + i * 8];
}

// ================= 256x256 8-phase GEMM (guide template, m201-class) =================
// C[M][N] = A[M][K] * BT[N][K]^T + bias. BK=64, 8 waves (2Mx4N), per-wave 128x64.
// LDS 128KB: A/B each [2 buf][256 rows][64 cols], rows 128B, granule^=(row&7) swizzle.
// Staged via global_load_lds w16 with pre-swizzled SOURCE (rule 21).
// Counted vmcnt(4) at phases 4/8 only, PINNED with sched_barrier(0) (rule 18-class
// compiler motion across bare inline-asm waitcnt was the R9 race).
#define BAR() __builtin_amdgcn_s_barrier()
#define PRIO1() __builtin_amdgcn_s_setprio(1)
#define PRIO0() __builtin_amdgcn_s_setprio(0)
#define SB0() __builtin_amdgcn_sched_barrier(0)
#define WVM(n)                                                                                    \
  do {                                                                                            \
    SB0();                                                                                        \
    asm volatile("s_waitcnt vmcnt(" #n ")" ::: "memory");                                         \
    SB0();                                                                                        \
  } while (0)

#define STG(mat, b0, h, T, ldsb)                                                                  \
  do {                                                                                            \
    _Pragma("unroll") for (int q = 0; q < 2; ++q) {                                               \
      int idx = q * 512 + tid;                                                                    \
      int rl = idx >> 3, gp = idx & 7;                                                            \
      const u16* s = (mat) + (size_t)((b0) + (h) * 128 + rl) * K + (T) * 64 +                     \
                     ((gp ^ (rl & 7)) << 3);                                                      \
      __builtin_amdgcn_global_load_lds((const __attribute__((address_space(1))) void*)s,          \
          (__attribute__((address_space(3))) void*)((ldsb) + (h) * 8192 + idx * 8), 16, 0, 0);    \
    }                                                                                             \
  } while (0)

#define LOAD_A(buf, mib)                                                                          \
  _Pragma("unroll") for (int mi = 0; mi < 4; ++mi)                                                \
  _Pragma("unroll") for (int ks = 0; ks < 2; ++ks)                                                \
    af[mi][ks] = *(const bf16x8*)((buf) + (wr * 128 + ((mib) + mi) * 16 + l15) * 64 +             \
                                  (((ks * 4 + lg) ^ (l15 & 7)) << 3));

#define LOAD_B(buf, nib)                                                                          \
  _Pragma("unroll") for (int ni = 0; ni < 2; ++ni)                                                \
  _Pragma("unroll") for (int ks = 0; ks < 2; ++ks)                                                \
    bfr[(nib) + ni][ks] = *(const bf16x8*)((buf) + (wc * 64 + ((nib) + ni) * 16 + l15) * 64 +     \
                                           (((ks * 4 + lg) ^ (l15 & 7)) << 3));

#define MFMA16(accb, nib)                                                                         \
  _Pragma("unroll") for (int mi = 0; mi < 4; ++mi)                                                \
  _Pragma("unroll") for (int ni = 0; ni < 2; ++ni)                                                \
  _Pragma("unroll") for (int ks = 0; ks < 2; ++ks)                                                \
    acc[(accb) + mi][(nib) + ni] = __builtin_amdgcn_mfma_f32_16x16x32_bf16(                       \
        af[mi][ks], bfr[(nib) + ni][ks], acc[(accb) + mi][(nib) + ni], 0, 0, 0);

template <bool OUT_F32>
__global__ __launch_bounds__(512, 2) void gemm256(const u16* __restrict__ A, const u16* __restrict__ BT,
                                                  const float* __restrict__ bias, void* __restrict__ Cout,
                                                  int M, int N, int K) {
  __shared__ u16 Asm[2][16384];
  __shared__ u16 Bsm[2][16384];
  int nwg = gridDim.x;
  int bid = (int)blockIdx.x;
  bid = (bid & 7) * (nwg >> 3) + (bid >> 3);  // XCD swizzle (nwg % 8 == 0)
  int ntn = N >> 8;
  int m0 = (bid / ntn) << 8, n0 = (bid % ntn) << 8;
  int tid = threadIdx.x, w = tid >> 6, lane = tid & 63;
  int wr = w >> 2, wc = w & 3;
  int l15 = lane & 15, lg = lane >> 4;
  int NT = K >> 6;
  u16* A0b = &Asm[0][0]; u16* A1b = &Asm[1][0];
  u16* B0b = &Bsm[0][0]; u16* B1b = &Bsm[1][0];
  f32x4 acc[8][4] = {};
  bf16x8 af[4][2], bfr[4][2];

  // prologue: tile0 full + A0,B0 of tile1 (A1,B1 of tile1 arrive in P1,P2)
  STG(A, m0, 0, 0, A0b); STG(A, m0, 1, 0, A0b);
  STG(BT, n0, 0, 0, B0b); STG(BT, n0, 1, 0, B0b);
  STG(A, m0, 0, 1, A1b); STG(BT, n0, 0, 1, B1b);
  WVM(0);
  BAR();

  for (int T = 0; T + 2 < NT; T += 2) {
    // P1: compute tile T quad (m0-63, n0-31)
    LOAD_A(A0b, 0); LOAD_B(B0b, 0);
    STG(A, m0, 1, T + 1, A1b);
    BAR(); PRIO1(); MFMA16(0, 0); PRIO0(); BAR();
    // P2: (m0-63, n32-63)
    LOAD_B(B0b, 2);
    STG(BT, n0, 1, T + 1, B1b);
    BAR(); PRIO1(); MFMA16(0, 2); PRIO0(); BAR();
    // P3: (m64-127, n0-31)
    LOAD_A(A0b, 4);
    STG(BT, n0, 0, T + 2, B0b);
    BAR(); PRIO1(); MFMA16(4, 0); PRIO0(); BAR();
    // P4: (m64-127, n32-63); ensure tile T+1 resident (newest 4 loads may fly)
    STG(A, m0, 0, T + 2, A0b);
    WVM(4);
    BAR(); PRIO1(); MFMA16(4, 2); PRIO0(); BAR();
    // P5-P8: tile T+1 from buf1
    LOAD_A(A1b, 0); LOAD_B(B1b, 0);
    STG(A, m0, 1, T + 2, A0b);
    BAR(); PRIO1(); MFMA16(0, 0); PRIO0(); BAR();
    LOAD_B(B1b, 2);
    STG(BT, n0, 1, T + 2, B0b);
    BAR(); PRIO1(); MFMA16(0, 2); PRIO0(); BAR();
    LOAD_A(A1b, 4);
    STG(BT, n0, 0, T + 3, B1b);
    BAR(); PRIO1(); MFMA16(4, 0); PRIO0(); BAR();
    STG(A, m0, 0, T + 3, A1b);
    WVM(4);
    BAR(); PRIO1(); MFMA16(4, 2); PRIO0(); BAR();
  }
  {  // epilogue: tiles NT-2 (buf0), NT-1 (buf1); drain staging before buf1 reads
    int T = NT - 2;
    LOAD_A(A0b, 0); LOAD_B(B0b, 0);
    STG(A, m0, 1, T + 1, A1b);
    BAR(); PRIO1(); MFMA16(0, 0); PRIO0(); BAR();
    LOAD_B(B0b, 2);
    STG(BT, n0, 1, T + 1, B1b);
    BAR(); PRIO1(); MFMA16(0, 2); PRIO0(); BAR();
    LOAD_A(A0b, 4);
    BAR(); PRIO1(); MFMA16(4, 0); PRIO0(); BAR();
    WVM(0);
    BAR(); PRIO1(); MFMA16(4, 2); PRIO0(); BAR();
    LOAD_A(A1b, 0); LOAD_B(B1b, 0);
    BAR(); PRIO1(); MFMA16(0, 0); PRIO0(); BAR();
    LOAD_B(B1b, 2);
    BAR(); PRIO1(); MFMA16(0, 2); PRIO0(); BAR();
    LOAD_A(A1b, 4);
    BAR(); PRIO1(); MFMA16(4, 0); PRIO0(); BAR();
    PRIO1(); MFMA16(4, 2); PRIO0();
  }
  // C write (same verified mapping as m97 kernel)
#pragma unroll
  for (int mi = 0; mi < 8; ++mi) {
    int mrow = m0 + wr * 128 + mi * 16 + lg * 4;
#pragma unroll
    for (int ni = 0; ni < 4; ++ni) {
      int col = n0 + wc * 64 + ni * 16 + l15;
      float bv = bias[col];
#pragma unroll
      for (int j = 0; j < 4; ++j) {
        float v = acc[mi][ni][j] + bv;
        if (OUT_F32)
          ((float*)Cout)[(size_t)(mrow + j) * N + col] = v;
        else
          ((u16*)Cout)[(size_t)(mrow + j) * N + col] = f2bf(v);
      }
    }
  }
}

// ---------------- RoPE + scatter qkv -> q_pack [b][s][h][d] / k / v (bf16) ----------------
__global__ void rope_scatter(const u16* __restrict__ qkv, const float* __restrict__ freqs,
                             u16* __restrict__ qo, u16* __restrict__ ko, u16* __restrict__ vo) {
  const int per_row = QKVN / 8;  // 320
  const int total = B_ * S_ * per_row;
  int i = blockIdx.x * blockDim.x + threadIdx.x;
  int stride = gridDim.x * blockDim.x;
  for (; i < total; i += stride) {
    int m = i / per_row;
    int n8 = (i - m * per_row) * 8;
    int b = m >> 11, s = m & 2047;
    uint4 raw = *(const uint4*)(qkv + (size_t)m * QKVN + n8);
    const u16* u = (const u16*)&raw;
    if (n8 < 2304) {
      int d = (n8 < 2048) ? (n8 & 255) : (n8 - 2048);
      float scl = (n8 < 2048) ? (0.0625f * 1.44269504f) : 1.0f;
      const float* fp = freqs + ((size_t)s * 128 + (d >> 1)) * 2;
      float4 f0 = *(const float4*)fp;
      float4 f1 = *(const float4*)(fp + 4);
      float fc[8] = {f0.x, f0.y, f0.z, f0.w, f1.x, f1.y, f1.z, f1.w};
      u16 o[8];
#pragma unroll
      for (int p = 0; p < 4; ++p) {
        float r = bf2f(u[2 * p]), im = bf2f(u[2 * p + 1]);
        float c = fc[2 * p], sn = fc[2 * p + 1];
        o[2 * p] = f2bf((r * c - im * sn) * scl);
        o[2 * p + 1] = f2bf((r * sn + im * c) * scl);
      }
      u16* dst;
      if (n8 < 2048) {
        dst = qo + (size_t)m * 2048 + n8;  // packed [b][s][h][d]
      } else {
        dst = ko + (((size_t)m) << 8) + d;
      }
      *(uint4*)dst = *(const uint4*)o;
    } else {
      int d = n8 - 2304;
      *(uint4*)(vo + (((size_t)m) << 8) + d) = raw;
    }
  }
}

// ---------------- flash attention core (R8-proven) ----------------
#define STAGE_K(bufofs, kt)                                                                       \
  do {                                                                                            \
    _Pragma("unroll") for (int _p = 0; _p < 4; ++_p) {                                            \
      int _idx = _p * 512 + tid;                                                                  \
      int _row = _idx >> 5, _c = _idx & 31;                                                       \
      const u16* _src = Kp + ((size_t)(b * S_ + (kt) * 64 + _row)) * HD_ +                        \
                        ((_c ^ (_row & 31)) * 8);                                                 \
      __builtin_amdgcn_global_load_lds(                                                           \
          (const __attribute__((address_space(1))) void*)_src,                                    \
          (__attribute__((address_space(3))) void*)(KsBase + (bufofs) + _idx * 8), 16, 0, 0);     \
    }                                                                                             \
  } while (0)

#define STAGE_V(bufofs, kt)                                                                       \
  do {                                                                                            \
    _Pragma("unroll") for (int _p = 0; _p < 4; ++_p) {                                            \
      int _idx = _p * 512 + tid;                                                                  \
      int _r = _idx >> 4, _gp = _idx & 15;                                                        \
      int _g = _gp ^ (_r & 15);                                                                   \
      int _d = _r * 2 + (_g >> 3), _c = _g & 7;                                                   \
      const u16* _src = VTp + ((size_t)(b * 256 + _d)) * S_ + (kt) * 64 + _c * 8;                 \
      __builtin_amdgcn_global_load_lds(                                                           \
          (const __attribute__((address_space(1))) void*)_src,                                    \
          (__attribute__((address_space(3))) void*)(VsBase + (bufofs) + _idx * 8), 16, 0, 0);     \
    }                                                                                             \
  } while (0)

// Core loop over kt in [kb, ke): updates m_r, l_r, oacc. Assumes kb < ke.
#define FLASH_SEG_BODY()                                                                          \
  STAGE_K(0, kb);                                                                                 \
  STAGE_V(0, kb);                                                                                 \
  __syncthreads();                                                                                \
  int cur = 0;                                                                                    \
  for (int kt = kb; kt < ke; ++kt) {                                                              \
    if (kt + 1 < ke) {                                                                            \
      STAGE_K((cur ^ 1) * 16384, kt + 1);                                                         \
      STAGE_V((cur ^ 1) * 16384, kt + 1);                                                         \
    }                                                                                             \
    const char* Kb = (const char*)(KsBase + cur * 16384);                                         \
    const char* Vb = (const char*)(VsBase + cur * 16384);                                         \
    _Pragma("unroll") for (int tau = 0; tau < 2; ++tau) {                                         \
      int k0 = kt * 64 + tau * 32;                                                                \
      if (k0 > t * 32 + 31) break;                                                                \
      int row = tau * 32 + l31;                                                                   \
      f32x16 scv = {};                                                                            \
      __builtin_amdgcn_s_setprio(1);                                                              \
      _Pragma("unroll") for (int st = 0; st < 16; ++st) {                                         \
        bf16x8 kf = *(const bf16x8*)(Kb + row * 512 + (((st * 2 + lh) ^ l31) << 4));              \
        scv = __builtin_amdgcn_mfma_f32_32x32x16_bf16(kf, qf[st], scv, 0, 0, 0);                  \
      }                                                                                           \
      __builtin_amdgcn_s_setprio(0);                                                              \
      if (k0 + 31 > t * 32) {                                                                     \
        _Pragma("unroll") for (int jj = 0; jj < 16; ++jj) {                                       \
          int kg = k0 + (jj & 3) + 8 * (jj >> 2) + 4 * lh;                                        \
          if (kg > s_g) scv[jj] = -3.0e38f;                                                       \
        }                                                                                         \
      }                                                                                           \
      float tmax = -3.0e38f;                                                                      \
      _Pragma("unroll") for (int jj = 0; jj < 16; ++jj) tmax = fmaxf(tmax, scv[jj]);              \
      tmax = fmaxf(tmax, __shfl_xor(tmax, 32));                                                   \
      if (!__all(tmax - m_r <= 8.0f)) {                                                           \
        float mnew = fmaxf(m_r, tmax);                                                            \
        float sc = exp2f(m_r - mnew);                                                             \
        l_r *= sc;                                                                                \
        _Pragma("unroll") for (int dt = 0; dt < 8; ++dt) oacc[dt] *= sc;                          \
        m_r = mnew;                                                                               \
      }                                                                                           \
      float ts = 0.f;                                                                             \
      unsigned cpk[8];                                                                            \
      _Pragma("unroll") for (int mi = 0; mi < 8; ++mi) {                                          \
        float p0 = exp2f(scv[2 * mi] - m_r);                                                      \
        float p1 = exp2f(scv[2 * mi + 1] - m_r);                                                  \
        ts += p0 + p1;                                                                            \
        cpk[mi] = ((unsigned)f2bf(p1) << 16) | f2bf(p0);                                          \
      }                                                                                           \
      ts += __shfl_xor(ts, 32);                                                                   \
      l_r += ts;                                                                                  \
      asm volatile("v_permlane32_swap_b32 %0, %1" : "+v"(cpk[0]), "+v"(cpk[2]));                  \
      asm volatile("v_permlane32_swap_b32 %0, %1" : "+v"(cpk[1]), "+v"(cpk[3]));                  \
      asm volatile("v_permlane32_swap_b32 %0, %1" : "+v"(cpk[4]), "+v"(cpk[6]));                  \
      asm volatile("v_permlane32_swap_b32 %0, %1" : "+v"(cpk[5]), "+v"(cpk[7]));                  \
      union { unsigned u[4]; bf16x8 v; } pa, pb;                                                  \
      pa.u[0] = cpk[0]; pa.u[1] = cpk[1]; pa.u[2] = cpk[2]; pa.u[3] = cpk[3];                     \
      pb.u[0] = cpk[4]; pb.u[1] = cpk[5]; pb.u[2] = cpk[6]; pb.u[3] = cpk[7];                     \
      __builtin_amdgcn_s_setprio(1);                                                              \
      _Pragma("unroll") for (int dt = 0; dt < 8; ++dt) {                                          \
        int d = dt * 32 + l31;                                                                    \
        int rr = d >> 1;                                                                          \
        int gb = (d & 1) * 8 + tau * 4;                                                           \
        int rx = (rr & 15) << 4;                                                                  \
        bf16x8 va = *(const bf16x8*)(Vb + rr * 256 + (((gb + lh) << 4) ^ rx));                    \
        oacc[dt] = __builtin_amdgcn_mfma_f32_32x32x16_bf16(va, pa.v, oacc[dt], 0, 0, 0);          \
        bf16x8 vb2 = *(const bf16x8*)(Vb + rr * 256 + (((gb + 2 + lh) << 4) ^ rx));               \
        oacc[dt] = __builtin_amdgcn_mfma_f32_32x32x16_bf16(vb2, pb.v, oacc[dt], 0, 0, 0);         \
      }                                                                                           \
      __builtin_amdgcn_s_setprio(0);                                                              \
    }                                                                                             \
    __syncthreads();                                                                              \
    cur ^= 1;                                                                                     \
  }

// ---------------- fallback flash (full range per tile) ----------------
__global__ __launch_bounds__(512, 2) void flash_attn(const u16* __restrict__ Qp, const u16* __restrict__ Kp,
                                                     const u16* __restrict__ VTp, u16* __restrict__ Op) {
  __shared__ u16 Ks[2][64 * 256];
  __shared__ u16 Vs[2][128 * 128];
  int bid = (int)blockIdx.x;
  int b = bid & 3, t = bid >> 2;
  int tid = threadIdx.x;
  int w = tid >> 6, l = tid & 63;
  int l31 = l & 31, lh = l >> 5;
  int q_local = w * 32 + l31;
  size_t qrow = (size_t)b * 16384 + (size_t)t * 256 + q_local;
  int s_g = t * 32 + (q_local >> 3);
  u16* KsBase = &Ks[0][0];
  u16* VsBase = &Vs[0][0];
  bf16x8 qf[16];
  const u16* qp = Qp + qrow * HD_ + lh * 8;
#pragma unroll
  for (int st = 0; st < 16; ++st) qf[st] = *(const bf16x8*)(qp + st * 16);
  f32x16 oacc[8] = {};
  float m_r = -3.0e38f, l_r = 0.f;
  int kb = 0, ke = t / 2 + 1;
  FLASH_SEG_BODY();
  float inv = 1.0f / l_r;
  u16* ob = Op + qrow * 256;
#pragma unroll
  for (int dt = 0; dt < 8; ++dt) {
#pragma unroll
    for (int jj = 0; jj < 4; ++jj) {
      int d0 = dt * 32 + jj * 8 + 4 * lh;
      u16 o4[4];
#pragma unroll
      for (int e = 0; e < 4; ++e) o4[e] = f2bf(oacc[dt][jj * 4 + e] * inv);
      *(ull*)(ob + d0) = *(const ull*)o4;
    }
  }
}

// ---------------- split-kv flash: block j does (tile j, part0) + (tile 63-j, part1) ----------------
__global__ __launch_bounds__(512, 2) void flash_attn_split(const u16* __restrict__ Qp, const u16* __restrict__ Kp,
                                                           const u16* __restrict__ VTp, u16* __restrict__ P0,
                                                           float* __restrict__ ml0, float* __restrict__ ml1,
                                                           u16* __restrict__ Op) {
  __shared__ u16 Ks[2][64 * 256];
  __shared__ u16 Vs[2][128 * 128];
  int bid = (int)blockIdx.x;
  int b = (bid & 7) >> 1;
  int j = ((bid & 1) << 5) + (bid >> 3);  // 0..63
  int tid = threadIdx.x;
  int w = tid >> 6, l = tid & 63;
  int l31 = l & 31, lh = l >> 5;
  int q_local = w * 32 + l31;
  u16* KsBase = &Ks[0][0];
  u16* VsBase = &Vs[0][0];

  for (int seg = 0; seg < 2; ++seg) {
    int t = seg ? (63 - j) : j;
    int nkv = (t >> 1) + 1;
    int half = (nkv + 1) >> 1;
    int kb = seg ? half : 0;
    int ke = seg ? nkv : half;
    size_t qrow = (size_t)b * 16384 + (size_t)t * 256 + q_local;
    int s_g = t * 32 + (q_local >> 3);
    float* mlbuf = seg ? ml1 : ml0;
    if (kb >= ke) {
      if (lh == 0) { mlbuf[qrow * 2] = -3.0e38f; mlbuf[qrow * 2 + 1] = 0.f; }
      continue;
    }
    bf16x8 qf[16];
    const u16* qp = Qp + qrow * HD_ + lh * 8;
#pragma unroll
    for (int st = 0; st < 16; ++st) qf[st] = *(const bf16x8*)(qp + st * 16);
    f32x16 oacc[8] = {};
    float m_r = -3.0e38f, l_r = 0.f;
    FLASH_SEG_BODY();
    float inv = 1.0f / l_r;
    u16* ob = (seg ? Op : P0) + qrow * 256;
#pragma unroll
    for (int dt = 0; dt < 8; ++dt) {
#pragma unroll
      for (int jj = 0; jj < 4; ++jj) {
        int d0 = dt * 32 + jj * 8 + 4 * lh;
        u16 o4[4];
#pragma unroll
        for (int e = 0; e < 4; ++e) o4[e] = f2bf(oacc[dt][jj * 4 + e] * inv);
        *(ull*)(ob + d0) = *(const ull*)o4;
      }
    }
    if (lh == 0) { mlbuf[qrow * 2] = m_r; mlbuf[qrow * 2 + 1] = l_r; }
  }
}

// ---------------- combine (coalesced): thread = (row, 16B col chunk) ----------------
__global__ __launch_bounds__(256) void combine_parts(const u16* __restrict__ P0, const float* __restrict__ ml0,
                                                     const float* __restrict__ ml1, u16* __restrict__ O) {
  int idx = blockIdx.x * 256 + threadIdx.x;  // 65536 rows * 32 chunks
  int r = idx >> 5;
  int c = (idx & 31) * 8;
  float m0 = ml0[(size_t)r * 2], l0 = ml0[(size_t)r * 2 + 1];
  float m1 = ml1[(size_t)r * 2], l1 = ml1[(size_t)r * 2 + 1];
  float M = fmaxf(m0, m1);
  float w0 = l0 * exp2f(m0 - M), w1 = l1 * exp2f(m1 - M);
  float inv = 1.0f / (w0 + w1);
  w0 *= inv; w1 *= inv;
  uint4 a = *(const uint4*)(P0 + (size_t)r * 256 + c);
  uint4 bq = *(const uint4*)(O + (size_t)r * 256 + c);
  const u16* ua = (const u16*)&a;
  const u16* ub = (const u16*)&bq;
  u16 o[8];
#pragma unroll
  for (int e = 0; e < 8; ++e) o[e] = f2bf(w0 * bf2f(ua[e]) + w1 * bf2f(ub[e]));
  *(uint4*)(O + (size_t)r * 256 + c) = *(const uint4*)o;
}

extern "C" void kernel_launch(void* const* d_in, const int* in_sizes, int n_in,
                              void* d_out, int out_size, void* d_ws, size_t ws_size,
                              hipStream_t stream) {
  const float* x = (const float*)d_in[0];
  const float* w_qkv = (const float*)d_in[1];
  const float* b_qkv = (const float*)d_in[2];
  const float* w_o = (const float*)d_in[3];
  const float* b_o = (const float*)d_in[4];
  const float* freqs = (const float*)d_in[5];
  // d_in[6] is the causal mask; causality is implemented directly.

  char* ws = (char*)d_ws;
  u16* xb    = (u16*)ws;                          // 33,554,432 B
  u16* wqkvT = (u16*)(ws + 33554432);             // 10,485,760 B
  u16* woT   = (u16*)(ws + 44040192);             //  8,388,608 B
  u16* qkv   = (u16*)(ws + 52428800);             // 41,943,040 B
  u16* qall  = (u16*)(ws + 94371840);             // 33,554,432 B
  u16* kbuf  = (u16*)(ws + 127926272);            //  4,194,304 B
  u16* vbuf  = (u16*)(ws + 132120576);            //  4,194,304 B
  u16* part0 = (u16*)(ws + 136314880);            // 33,554,432 B (split path only)
  float* ml0 = (float*)(ws + 169869312);          //    524,288 B
  float* ml1 = (float*)(ws + 170393600);          //    524,288 B  -> need 170,917,888
  u16* vT    = xb;    // alias: xb dead after QKV GEMM
  u16* attout = qkv;  // alias: qkv dead after rope_scatter

  bool split = (ws_size >= 170917888ULL);

  cast_f32_bf16<<<2048, 256, 0, stream>>>(x, xb, (B_ * S_ * HID_) / 8);
  transpose_cast<<<dim3(QKVN / 32, HID_ / 32), dim3(32, 8), 0, stream>>>(w_qkv, wqkvT, HID_, QKVN);
  transpose_cast<<<dim3(HID_ / 32, HID_ / 32), dim3(32, 8), 0, stream>>>(w_o, woT, HID_, HID_);
  gemm256<false><<<dim3(32 * 10), 512, 0, stream>>>(xb, wqkvT, b_qkv, qkv, B_ * S_, QKVN, HID_);
  rope_scatter<<<2048, 256, 0, stream>>>(qkv, freqs, qall, kbuf, vbuf);
  transpose_bf16<<<dim3(HD_ / 32, S_ / 32, B_), dim3(32, 8), 0, stream>>>(vbuf, vT, S_, HD_);
  if (split) {
    flash_attn_split<<<256, 512, 0, stream>>>(qall, kbuf, vT, part0, ml0, ml1, attout);
    combine_parts<<<8192, 256, 0, stream>>>(part0, ml0, ml1, attout);
  } else {
    flash_attn<<<256, 512, 0, stream>>>(qall, kbuf, vT, attout);
  }
  gemm256<true><<<dim3(32 * 8), 512, 0, stream>>>(attout, woT, b_o, d_out, B_ * S_, HID_, HID_);
}